// Round 6
// baseline (679.792 us; speedup 1.0000x reference)
//
#include <hip/hip_runtime.h>
#include <hip/hip_bf16.h>

// ---------------------------------------------------------------------------
// MatGCN: 4-layer GCN (D=128) + LN + residual + mean-pool + linear head.
// R22: fuse the layer-(L+1) matmul into layer-L k_node. R21's coop null
// proved dispatch boundaries ~ free, so R19's missing ~250us sits in the 4
// k_matmul dispatches (~50-60us each vs 8us roofline). h = y @ W is
// row-local and k_node's block owns exactly 16 rows = one MFMA tile:
// stage y (bf16) to LDS, 4 waves x 2 col-blocks x 4 kb MFMA with frag-packed
// Wt (L2-hot), C through LDS -> coalesced hb stores (double-buffered hb).
// Standalone k_matmul remains only for layer 0 (fp32 x). Numerics identical
// (y already bf16-rounded). Prep/pool unchanged from R19.
// ---------------------------------------------------------------------------

typedef __hip_bfloat162 bf2;
typedef __attribute__((ext_vector_type(8))) short short8;
typedef __attribute__((ext_vector_type(4))) float f32x4;

__global__ __launch_bounds__(256) void k_deg(const int* __restrict__ dst,
                                             int* __restrict__ cnt, int E) {
    int base = (blockIdx.x * 256 + threadIdx.x) * 4;
    if (base + 4 <= E) {
        int4 d4 = *(const int4*)(dst + base);
        atomicAdd(&cnt[d4.x], 1);
        atomicAdd(&cnt[d4.y], 1);
        atomicAdd(&cnt[d4.z], 1);
        atomicAdd(&cnt[d4.w], 1);
    } else {
        for (int j = base; j < E; j++) atomicAdd(&cnt[dst[j]], 1);
    }
}

__global__ __launch_bounds__(256) void k_scan1(const int* __restrict__ cnt,
                                               int* __restrict__ loc,
                                               int* __restrict__ blk,
                                               float* __restrict__ dis, int n) {
    __shared__ int s[256];
    int b = blockIdx.x, tid = threadIdx.x;
    int base = b * 1024 + tid * 4;
    int v0 = (base + 0 < n) ? cnt[base + 0] : 0;
    int v1 = (base + 1 < n) ? cnt[base + 1] : 0;
    int v2 = (base + 2 < n) ? cnt[base + 2] : 0;
    int v3 = (base + 3 < n) ? cnt[base + 3] : 0;
    if (base + 0 < n) dis[base + 0] = rsqrtf((float)v0 + 1.0f);
    if (base + 1 < n) dis[base + 1] = rsqrtf((float)v1 + 1.0f);
    if (base + 2 < n) dis[base + 2] = rsqrtf((float)v2 + 1.0f);
    if (base + 3 < n) dis[base + 3] = rsqrtf((float)v3 + 1.0f);
    int tsum = v0 + v1 + v2 + v3;
    s[tid] = tsum;
    __syncthreads();
    for (int off = 1; off < 256; off <<= 1) {
        int t = (tid >= off) ? s[tid - off] : 0;
        __syncthreads();
        s[tid] += t;
        __syncthreads();
    }
    int excl = s[tid] - tsum;
    if (base + 0 < n) loc[base + 0] = excl;
    if (base + 1 < n) loc[base + 1] = excl + v0;
    if (base + 2 < n) loc[base + 2] = excl + v0 + v1;
    if (base + 3 < n) loc[base + 3] = excl + v0 + v1 + v2;
    if (tid == 255) blk[b] = s[255];
}

__global__ __launch_bounds__(128) void k_scan2(int* __restrict__ blk, int nb,
                                               int* __restrict__ total_out) {
    __shared__ int s[128];
    int tid = threadIdx.x;
    int v = (tid < nb) ? blk[tid] : 0;
    s[tid] = v;
    __syncthreads();
    for (int off = 1; off < 128; off <<= 1) {
        int t = (tid >= off) ? s[tid - off] : 0;
        __syncthreads();
        s[tid] += t;
        __syncthreads();
    }
    if (tid < nb) blk[tid] = s[tid] - v;
    if (tid == 127) *total_out = s[127];
}

__global__ void k_scan3(int* __restrict__ row_off, const int* __restrict__ blk,
                        int* __restrict__ cur, int n) {
    int d = blockIdx.x * blockDim.x + threadIdx.x;
    if (d >= n) return;
    int ro = row_off[d] + blk[d >> 10];
    row_off[d] = ro;
    cur[d] = ro;
}

__global__ __launch_bounds__(256) void k_scatter2(const int* __restrict__ src,
                                                  const int* __restrict__ dst,
                                                  int* __restrict__ cur,
                                                  const float* __restrict__ dis,
                                                  int2* __restrict__ colcf, int E) {
    int base = (blockIdx.x * 256 + threadIdx.x) * 4;
    if (base + 4 <= E) {
        int4 d4 = *(const int4*)(dst + base);
        int4 s4 = *(const int4*)(src + base);
        int dd[4] = {d4.x, d4.y, d4.z, d4.w};
        int ss[4] = {s4.x, s4.y, s4.z, s4.w};
#pragma unroll
        for (int j = 0; j < 4; j++) {
            int p = atomicAdd(&cur[dd[j]], 1);
            float cf = dis[ss[j]] * dis[dd[j]];
            colcf[p] = make_int2(ss[j], __float_as_int(cf));
        }
    } else {
        for (int j = base; j < E; j++) {
            int d = dst[j], s = src[j];
            int p = atomicAdd(&cur[d], 1);
            colcf[p] = make_int2(s, __float_as_int(dis[s] * dis[d]));
        }
    }
}

// Wt packed in MFMA B-fragment order:
// Wt[layer][((c*4+kb)*64 + lane)*8 + j] = bf16(W[layer][kb*32+(lane>>4)*8+j][c*16+(lane&15)])
__global__ void k_prepw(const float* __restrict__ Ws, __hip_bfloat16* __restrict__ Wt) {
    int i = blockIdx.x * blockDim.x + threadIdx.x;   // 4*16384
    int layer = i >> 14;
    int m = i & 16383;
    int j = m & 7;
    int l = (m >> 3) & 63;
    int ckb = m >> 9;
    int kb = ckb & 3;
    int c = ckb >> 2;
    int quad = l >> 4, lr = l & 15;
    int k = kb * 32 + quad * 8 + j;
    int col = c * 16 + lr;
    Wt[i] = __float2bfloat16(Ws[layer * 16384 + k * 128 + col]);
}

// Layer-0 only: H0 = bf16(x) @ W0. 64 rows/block.
__global__ __launch_bounds__(256) void k_matmul(const float* __restrict__ Xf,
                                                const __hip_bfloat16* __restrict__ Wt,
                                                __hip_bfloat16* __restrict__ Hb, int n) {
    __shared__ __align__(16) __hip_bfloat16 sX[64 * 136];
    const int tid = threadIdx.x;
    const int row0 = blockIdx.x * 64;
    for (int i = tid; i < 2048; i += 256) {
        int r = i >> 5, c = i & 31;
        int gr = row0 + r;
        float4 v = make_float4(0.f, 0.f, 0.f, 0.f);
        if (gr < n) v = *(const float4*)(Xf + (size_t)gr * 128 + c * 4);
        union { bf2 h2[2]; uint2 u; } pk;
        pk.h2[0].x = __float2bfloat16(v.x);
        pk.h2[0].y = __float2bfloat16(v.y);
        pk.h2[1].x = __float2bfloat16(v.z);
        pk.h2[1].y = __float2bfloat16(v.w);
        *(uint2*)(sX + r * 136 + c * 4) = pk.u;
    }
    __syncthreads();
    const int w = tid >> 6, l = tid & 63;
    const int quad = l >> 4, lr = l & 15;
    f32x4 acc[8];
#pragma unroll
    for (int c = 0; c < 8; c++) acc[c] = (f32x4){0.f, 0.f, 0.f, 0.f};
    short8 a[4];
#pragma unroll
    for (int kb = 0; kb < 4; kb++)
        a[kb] = *(const short8*)(sX + (w * 16 + lr) * 136 + kb * 32 + quad * 8);
#pragma unroll
    for (int c = 0; c < 8; c++) {
#pragma unroll
        for (int kb = 0; kb < 4; kb++) {
            short8 b = *(const short8*)(Wt + ((c * 4 + kb) * 64 + l) * 8);
            acc[c] = __builtin_amdgcn_mfma_f32_16x16x32_bf16(a[kb], b, acc[c], 0, 0, 0);
        }
    }
#pragma unroll
    for (int c = 0; c < 8; c++)
#pragma unroll
        for (int r = 0; r < 4; r++)
            sX[(w * 16 + quad * 4 + r) * 136 + c * 16 + lr] =
                __float2bfloat16(acc[c][r]);
#pragma unroll
    for (int p = 0; p < 4; p++) {
        int r = p * 4 + quad;
        int gr = row0 + w * 16 + r;
        uint4 v = *(const uint4*)(sX + (w * 16 + r) * 136 + lr * 8);
        if (gr < n) *(uint4*)(Hb + (size_t)gr * 128 + lr * 8) = v;
    }
}

// k_nodeF: gather + LN + residual (+relu) per node, then (do_mm) the NEXT
// layer's matmul for this block's 16 rows via MFMA, or (fuse_pool) the
// pooled dot. Lane mapping (grp = lane>>4 = A-frag quad, sub = lane&15 =
// A-frag row) makes y-in-LDS directly readable as A fragments.
__global__ __launch_bounds__(256) void k_nodeF(const __hip_bfloat16* __restrict__ Hin,
                                               __hip_bfloat16* __restrict__ Hout,
                                               __hip_bfloat16* __restrict__ Xb,
                                               const int* __restrict__ row_off,
                                               const int2* __restrict__ colcf,
                                               const float* __restrict__ dis,
                                               const float* __restrict__ bias,
                                               const float* __restrict__ gamma,
                                               const float* __restrict__ beta,
                                               const __hip_bfloat16* __restrict__ wnext,
                                               const float* __restrict__ lin_w,
                                               const int* __restrict__ batch,
                                               float* __restrict__ gsum,
                                               int do_relu, int do_res, int do_mm,
                                               int fuse_pool, int n) {
    __shared__ __align__(16) __hip_bfloat16 sY[16 * 136];
    __shared__ __align__(16) __hip_bfloat16 sH[16 * 136];
    __shared__ float spd[16];
    __shared__ int   sbt[16];
    const int tid = threadIdx.x;
    const int wv = tid >> 6;
    const int lane = tid & 63;
    const int grp = lane >> 4;      // == quad
    const int sub = lane & 15;      // == lr
    const int node = blockIdx.x * 16 + wv * 4 + grp;
    const bool vn = node < n;
    const int nd = vn ? node : 0;
    const int e0 = vn ? row_off[node] : 0;
    const int e1 = vn ? row_off[node + 1] : 0;
    const char* hbase = (const char*)Hin;
    const unsigned suboff = (unsigned)(sub << 4);

    float dn = dis[nd];
    uint4 sv = *(const uint4*)(hbase + (((unsigned)nd) << 8) + suboff);

    float acc[8];
#pragma unroll
    for (int k = 0; k < 8; k++) acc[k] = 0.f;

    int e = e0;
    int2 p[8];
#pragma unroll
    for (int u = 0; u < 8; u++) p[u] = colcf[(e + u < e1) ? e + u : 0];

    while (__any(e < e1)) {
        uint4 v[8];
        float cf[8];
#pragma unroll
        for (int u = 0; u < 8; u++) {
            v[u] = *(const uint4*)(hbase + (((unsigned)p[u].x) << 8) + suboff);
            cf[u] = (e + u < e1) ? __int_as_float(p[u].y) : 0.f;
        }
        const int en = e + 8;
        int2 pn[8];
#pragma unroll
        for (int u = 0; u < 8; u++) pn[u] = colcf[(en + u < e1) ? en + u : 0];
#pragma unroll
        for (int u = 0; u < 8; u++) {
            float c = cf[u];
            acc[0] += __uint_as_float(v[u].x << 16) * c;
            acc[1] += __uint_as_float(v[u].x & 0xffff0000u) * c;
            acc[2] += __uint_as_float(v[u].y << 16) * c;
            acc[3] += __uint_as_float(v[u].y & 0xffff0000u) * c;
            acc[4] += __uint_as_float(v[u].z << 16) * c;
            acc[5] += __uint_as_float(v[u].z & 0xffff0000u) * c;
            acc[6] += __uint_as_float(v[u].w << 16) * c;
            acc[7] += __uint_as_float(v[u].w & 0xffff0000u) * c;
        }
#pragma unroll
        for (int u = 0; u < 8; u++) p[u] = pn[u];
        e = en;
    }

    {   // self-loop (preloaded)
        float dn2 = dn * dn;
        acc[0] += __uint_as_float(sv.x << 16) * dn2;
        acc[1] += __uint_as_float(sv.x & 0xffff0000u) * dn2;
        acc[2] += __uint_as_float(sv.y << 16) * dn2;
        acc[3] += __uint_as_float(sv.y & 0xffff0000u) * dn2;
        acc[4] += __uint_as_float(sv.z << 16) * dn2;
        acc[5] += __uint_as_float(sv.z & 0xffff0000u) * dn2;
        acc[6] += __uint_as_float(sv.w << 16) * dn2;
        acc[7] += __uint_as_float(sv.w & 0xffff0000u) * dn2;
    }
    float4 b0 = *(const float4*)(bias + sub * 8);
    float4 b1 = *(const float4*)(bias + sub * 8 + 4);
    acc[0] += b0.x; acc[1] += b0.y; acc[2] += b0.z; acc[3] += b0.w;
    acc[4] += b1.x; acc[5] += b1.y; acc[6] += b1.z; acc[7] += b1.w;

    // LayerNorm within the 16-lane group
    float s = acc[0] + acc[1] + acc[2] + acc[3] + acc[4] + acc[5] + acc[6] + acc[7];
#pragma unroll
    for (int m = 8; m > 0; m >>= 1) s += __shfl_xor(s, m, 64);
    float mu = s * (1.f / 128.f);
    float vs = 0.f;
#pragma unroll
    for (int k = 0; k < 8; k++) {
        float d = acc[k] - mu;
        acc[k] = d;
        vs += d * d;
    }
#pragma unroll
    for (int m = 8; m > 0; m >>= 1) vs += __shfl_xor(vs, m, 64);
    float rs = rsqrtf(vs * (1.f / 128.f) + 1e-5f);

    float4 g0 = *(const float4*)(gamma + sub * 8);
    float4 g1 = *(const float4*)(gamma + sub * 8 + 4);
    float4 t0 = *(const float4*)(beta + sub * 8);
    float4 t1 = *(const float4*)(beta + sub * 8 + 4);
    float y[8];
    y[0] = acc[0] * rs * g0.x + t0.x;
    y[1] = acc[1] * rs * g0.y + t0.y;
    y[2] = acc[2] * rs * g0.z + t0.z;
    y[3] = acc[3] * rs * g0.w + t0.w;
    y[4] = acc[4] * rs * g1.x + t1.x;
    y[5] = acc[5] * rs * g1.y + t1.y;
    y[6] = acc[6] * rs * g1.z + t1.z;
    y[7] = acc[7] * rs * g1.w + t1.w;

    __hip_bfloat16* xp = Xb + (size_t)node * 128 + sub * 8;
    if (vn && do_res) {
        uint4 rv = *(const uint4*)xp;
        y[0] += __uint_as_float(rv.x << 16);
        y[1] += __uint_as_float(rv.x & 0xffff0000u);
        y[2] += __uint_as_float(rv.y << 16);
        y[3] += __uint_as_float(rv.y & 0xffff0000u);
        y[4] += __uint_as_float(rv.z << 16);
        y[5] += __uint_as_float(rv.z & 0xffff0000u);
        y[6] += __uint_as_float(rv.w << 16);
        y[7] += __uint_as_float(rv.w & 0xffff0000u);
    }
    if (do_relu) {
#pragma unroll
        for (int k = 0; k < 8; k++) y[k] = fmaxf(y[k], 0.f);
    }

    // bf16 pack of y (used for xb store, LDS stage, both)
    union { bf2 h2[4]; uint4 u; } pk;
    pk.h2[0].x = __float2bfloat16(y[0]); pk.h2[0].y = __float2bfloat16(y[1]);
    pk.h2[1].x = __float2bfloat16(y[2]); pk.h2[1].y = __float2bfloat16(y[3]);
    pk.h2[2].x = __float2bfloat16(y[4]); pk.h2[2].y = __float2bfloat16(y[5]);
    pk.h2[3].x = __float2bfloat16(y[6]); pk.h2[3].y = __float2bfloat16(y[7]);

    if (fuse_pool) {
        float4 w0 = *(const float4*)(lin_w + sub * 8);
        float4 w1 = *(const float4*)(lin_w + sub * 8 + 4);
        float pdot = y[0] * w0.x + y[1] * w0.y + y[2] * w0.z + y[3] * w0.w +
                     y[4] * w1.x + y[5] * w1.y + y[6] * w1.z + y[7] * w1.w;
#pragma unroll
        for (int m = 8; m > 0; m >>= 1) pdot += __shfl_xor(pdot, m, 64);
        int slot = wv * 4 + grp;
        if (sub == 0) {
            spd[slot] = vn ? pdot : 0.f;
            sbt[slot] = vn ? batch[node] : -1;
        }
        __syncthreads();
        if (tid == 0) {
            int i = 0;
            while (i < 16) {
                int b = sbt[i];
                if (b < 0) { i++; continue; }
                float acc2 = spd[i];
                int j = i + 1;
                while (j < 16 && sbt[j] == b) { acc2 += spd[j]; j++; }
                atomicAdd(&gsum[b], acc2);
                i = j;
            }
        }
        return;
    }

    if (vn) *(uint4*)xp = pk.u;

    if (do_mm) {
        // Stage y rows (bf16) -> sY[16][136]; invalid rows zeroed.
        uint4 zero = make_uint4(0, 0, 0, 0);
        *(uint4*)(sY + (wv * 4 + grp) * 136 + sub * 8) = vn ? pk.u : zero;
        __syncthreads();
        // A-fragments: row = sub, k = kb*32 + grp*8 + j
        short8 a[4];
#pragma unroll
        for (int kb = 0; kb < 4; kb++)
            a[kb] = *(const short8*)(sY + sub * 136 + kb * 32 + grp * 8);
        f32x4 hacc[2];
#pragma unroll
        for (int ci = 0; ci < 2; ci++) hacc[ci] = (f32x4){0.f, 0.f, 0.f, 0.f};
#pragma unroll
        for (int ci = 0; ci < 2; ci++) {
            const int c = wv * 2 + ci;
#pragma unroll
            for (int kb = 0; kb < 4; kb++) {
                short8 b = *(const short8*)(wnext + ((c * 4 + kb) * 64 + lane) * 8);
                hacc[ci] = __builtin_amdgcn_mfma_f32_16x16x32_bf16(a[kb], b, hacc[ci], 0, 0, 0);
            }
        }
        // C layout: col = sub, row = grp*4 + r  -> stage to sH
#pragma unroll
        for (int ci = 0; ci < 2; ci++) {
            const int c = wv * 2 + ci;
#pragma unroll
            for (int r = 0; r < 4; r++)
                sH[(grp * 4 + r) * 136 + c * 16 + sub] = __float2bfloat16(hacc[ci][r]);
        }
        __syncthreads();
        // Coalesced store: 16 rows x 16 uint4, one per thread.
        int row = tid >> 4, ck = tid & 15;
        int gr = blockIdx.x * 16 + row;
        if (gr < n) {
            uint4 v = *(const uint4*)(sH + row * 136 + ck * 8);
            *(uint4*)(Hout + (size_t)gr * 128 + ck * 8) = v;
        }
    }
}

__global__ void k_out(const float* __restrict__ gsum, const int* __restrict__ batch,
                      const float* __restrict__ lin_b, float* __restrict__ out,
                      int n, int G) {
    int g = blockIdx.x * blockDim.x + threadIdx.x;
    if (g >= G) return;
    int lo = 0, hi = n;
    while (lo < hi) { int m = (lo + hi) >> 1; if (batch[m] < g) lo = m + 1; else hi = m; }
    int start = lo;
    hi = n;
    while (lo < hi) { int m = (lo + hi) >> 1; if (batch[m] <= g) lo = m + 1; else hi = m; }
    float c = (float)(lo - start);
    out[g] = gsum[g] / fmaxf(c, 1.f) + lin_b[0];
}

extern "C" void kernel_launch(void* const* d_in, const int* in_sizes, int n_in,
                              void* d_out, int out_size, void* d_ws, size_t ws_size,
                              hipStream_t stream) {
    const float* x      = (const float*)d_in[0];
    const int*   eidx   = (const int*)d_in[1];
    const int*   batch  = (const int*)d_in[2];
    const float* Ws     = (const float*)d_in[3];
    const float* bs     = (const float*)d_in[4];
    const float* gammas = (const float*)d_in[5];
    const float* betas  = (const float*)d_in[6];
    const float* lin_w  = (const float*)d_in[7];
    const float* lin_b  = (const float*)d_in[8];
    float* out = (float*)d_out;

    const int n = in_sizes[2];        // 100000
    const int E = in_sizes[1] / 2;    // 1600000
    const int G = out_size;           // 512
    const int nb = (n + 1023) / 1024;

    const int* src  = eidx;
    const int* dstp = eidx + E;

    char* w = (char*)d_ws;
    size_t off = 0;
    auto alloc = [&](size_t bytes) {
        void* p = w + off;
        off = (off + bytes + 15) & ~(size_t)15;
        return p;
    };
    int*   cnt     = (int*)  alloc((size_t)n * 4);
    float* gsum    = (float*)alloc((size_t)G * 4);     // contiguous after cnt -> one memset
    int*   row_off = (int*)  alloc((size_t)(n + 1) * 4);
    int*   blkarr  = (int*)  alloc(128 * 4);
    int*   cur     = (int*)  alloc((size_t)n * 4);
    float* dis     = (float*)alloc((size_t)n * 4);
    int2*  colcf   = (int2*) alloc((size_t)E * 8);
    __hip_bfloat16* hbA = (__hip_bfloat16*)alloc((size_t)n * 128 * 2);
    __hip_bfloat16* hbB = (__hip_bfloat16*)alloc((size_t)n * 128 * 2);
    __hip_bfloat16* xb  = (__hip_bfloat16*)alloc((size_t)n * 128 * 2);
    __hip_bfloat16* wt  = (__hip_bfloat16*)alloc((size_t)4 * 128 * 128 * 2);
    (void)ws_size; (void)n_in;

    hipMemsetAsync(cnt, 0, (size_t)n * 4 + (size_t)G * 4, stream);
    k_deg<<<(E + 1023) / 1024, 256, 0, stream>>>(dstp, cnt, E);
    k_scan1<<<nb, 256, 0, stream>>>(cnt, row_off, blkarr, dis, n);
    k_scan2<<<1, 128, 0, stream>>>(blkarr, nb, row_off + n);
    k_scan3<<<(n + 255) / 256, 256, 0, stream>>>(row_off, blkarr, cur, n);
    k_scatter2<<<(E + 1023) / 1024, 256, 0, stream>>>(src, dstp, cur, dis, colcf, E);
    k_prepw<<<(4 * 128 * 128 + 255) / 256, 256, 0, stream>>>(Ws, wt);

    // Layer 0 matmul from fp32 x -> hbA
    k_matmul<<<(n + 63) / 64, 256, 0, stream>>>(x, wt, hbA, n);

    __hip_bfloat16* hin  = hbA;
    __hip_bfloat16* hout = hbB;
    for (int layer = 0; layer < 4; layer++) {
        const int do_mm = (layer < 3);
        k_nodeF<<<(n + 15) / 16, 256, 0, stream>>>(
            hin, hout, xb, row_off, colcf, dis,
            bs + (size_t)layer * 128,
            gammas + (size_t)layer * 128,
            betas + (size_t)layer * 128,
            wt + (size_t)(do_mm ? (layer + 1) : 0) * 16384,
            lin_w, batch, gsum,
            (layer < 3) ? 1 : 0, (layer > 0) ? 1 : 0, do_mm,
            (layer == 3) ? 1 : 0, n);
        __hip_bfloat16* t = hin; hin = hout; hout = t;
    }
    k_out<<<(G + 255) / 256, 256, 0, stream>>>(gsum, batch, lin_b, out, n, G);
}

// Round 8
// 553.630 us; speedup vs baseline: 1.2279x; 1.2279x over previous
//
#include <hip/hip_runtime.h>
#include <hip/hip_bf16.h>

// ---------------------------------------------------------------------------
// MatGCN: 4-layer GCN (D=128) + LN + residual + mean-pool + linear head.
// R24 (verbatim resubmit of R23; prior bench lost to container-level infra
// failure — kernel re-audited: no hang paths, no OOB, 22.5KB LDS max,
// bounded loops, no coop launch). Prep rebuilt with ZERO global atomics:
//   p1a  512 blocks LDS-histogram edges into NB=ceil(n/256) buckets (dst>>8)
//   p1b1 per-bucket exclusive scan of the 512 block counts
//   p1b2 bucket-base scan + row_off[n]=E + gsum zeroing
//   p1c  re-read edges, LDS cursors, packed (dstLocal<<17|src) u32 scatter
//   p2   block per bucket: LDS hist->deg->dis, scan->row_off, coalesced
//        colsrc writes
// colcf(int2) -> colsrc(u32): k_node recomputes coef = dis[src]*dis[dst].
// k_matmul / k_node / k_out in proven R19 forms.
// ---------------------------------------------------------------------------

typedef __hip_bfloat162 bf2;
typedef __attribute__((ext_vector_type(8))) short short8;
typedef __attribute__((ext_vector_type(4))) float f32x4;

#define P1B 512           // phase-1 blocks
#define MAXB 5120         // max edges per bucket (mean 4092, +16 sigma)

// p1a: per-block LDS histogram of dst>>8 over its edge chunk.
__global__ __launch_bounds__(256) void k_p1a(const int* __restrict__ dst,
                                             int* __restrict__ bh, int E, int NB) {
    __shared__ int h[512];
    const int tid = threadIdx.x;
    for (int i = tid; i < NB; i += 256) h[i] = 0;
    __syncthreads();
    const int per = (((E + P1B - 1) / P1B) + 3) & ~3;
    const int e0 = blockIdx.x * per, e1 = min(E, e0 + per);
    for (int base = e0 + tid * 4; base < e1; base += 1024) {
        if (base + 4 <= e1) {
            int4 d4 = *(const int4*)(dst + base);
            atomicAdd(&h[d4.x >> 8], 1);
            atomicAdd(&h[d4.y >> 8], 1);
            atomicAdd(&h[d4.z >> 8], 1);
            atomicAdd(&h[d4.w >> 8], 1);
        } else {
            for (int j = base; j < e1; j++) atomicAdd(&h[dst[j] >> 8], 1);
        }
    }
    __syncthreads();
    int* out = bh + (size_t)blockIdx.x * NB;
    for (int i = tid; i < NB; i += 256) out[i] = h[i];
}

// p1b1: block b: exclusive scan of bh[blk][b] over blk=0..P1B-1 (in place);
// btot[b] = total.
__global__ __launch_bounds__(256) void k_p1b1(int* __restrict__ bh,
                                              int* __restrict__ btot, int NB) {
    __shared__ int s[256];
    const int b = blockIdx.x, tid = threadIdx.x;
    int v0 = bh[(size_t)(2 * tid) * NB + b];
    int v1 = bh[(size_t)(2 * tid + 1) * NB + b];
    int tsum = v0 + v1;
    s[tid] = tsum;
    __syncthreads();
    for (int off = 1; off < 256; off <<= 1) {
        int t = (tid >= off) ? s[tid - off] : 0;
        __syncthreads();
        s[tid] += t;
        __syncthreads();
    }
    int excl = s[tid] - tsum;
    bh[(size_t)(2 * tid) * NB + b] = excl;
    bh[(size_t)(2 * tid + 1) * NB + b] = excl + v0;
    if (tid == 255) btot[b] = s[255];
}

// p1b2: exclusive scan of btot -> bbase; row_off[n] = E; zero gsum.
__global__ __launch_bounds__(256) void k_p1b2(const int* __restrict__ btot,
                                              int* __restrict__ bbase,
                                              int* __restrict__ row_off,
                                              float* __restrict__ gsum,
                                              int NB, int E, int n, int G) {
    __shared__ int s[256];
    const int tid = threadIdx.x;
    int v0 = (2 * tid < NB) ? btot[2 * tid] : 0;
    int v1 = (2 * tid + 1 < NB) ? btot[2 * tid + 1] : 0;
    int tsum = v0 + v1;
    s[tid] = tsum;
    __syncthreads();
    for (int off = 1; off < 256; off <<= 1) {
        int t = (tid >= off) ? s[tid - off] : 0;
        __syncthreads();
        s[tid] += t;
        __syncthreads();
    }
    int excl = s[tid] - tsum;
    if (2 * tid < NB) bbase[2 * tid] = excl;
    if (2 * tid + 1 < NB) bbase[2 * tid + 1] = excl + v0;
    if (tid == 0) row_off[n] = E;
    for (int i = tid; i < G; i += 256) gsum[i] = 0.f;
}

// p1c: scatter packed edges into bucket regions via LDS cursors (no global
// atomics; per-(block,bucket) sub-ranges are disjoint by construction).
__global__ __launch_bounds__(256) void k_p1c(const int* __restrict__ src,
                                             const int* __restrict__ dst,
                                             const int* __restrict__ bh,
                                             const int* __restrict__ bbase,
                                             unsigned* __restrict__ ebuf,
                                             int E, int NB) {
    __shared__ int cur[512];
    const int tid = threadIdx.x;
    const int* cb = bh + (size_t)blockIdx.x * NB;
    for (int i = tid; i < NB; i += 256) cur[i] = cb[i] + bbase[i];
    __syncthreads();
    const int per = (((E + P1B - 1) / P1B) + 3) & ~3;
    const int e0 = blockIdx.x * per, e1 = min(E, e0 + per);
    for (int base = e0 + tid * 4; base < e1; base += 1024) {
        if (base + 4 <= e1) {
            int4 d4 = *(const int4*)(dst + base);
            int4 s4 = *(const int4*)(src + base);
            int dd[4] = {d4.x, d4.y, d4.z, d4.w};
            int ss[4] = {s4.x, s4.y, s4.z, s4.w};
#pragma unroll
            for (int j = 0; j < 4; j++) {
                int p = atomicAdd(&cur[dd[j] >> 8], 1);   // LDS atomic
                ebuf[p] = ((unsigned)(dd[j] & 255) << 17) | (unsigned)ss[j];
            }
        } else {
            for (int j = base; j < e1; j++) {
                int d = dst[j];
                int p = atomicAdd(&cur[d >> 8], 1);
                ebuf[p] = ((unsigned)(d & 255) << 17) | (unsigned)src[j];
            }
        }
    }
}

// p2: per bucket: LDS load, hist -> deg -> dis, scan -> row_off, LDS-cursor
// scatter -> coalesced colsrc writes.
__global__ __launch_bounds__(256) void k_p2(const unsigned* __restrict__ ebuf,
                                            const int* __restrict__ btot,
                                            const int* __restrict__ bbase,
                                            unsigned* __restrict__ colsrc,
                                            int* __restrict__ row_off,
                                            float* __restrict__ dis, int n) {
    __shared__ unsigned ein[MAXB];
    __shared__ int hist[256];
    __shared__ int scn[256];
    const int b = blockIdx.x, tid = threadIdx.x;
    const int base = bbase[b];
    int sz = btot[b];
    if (sz > MAXB) sz = MAXB;     // statistically impossible; guards LDS
    hist[tid] = 0;
    __syncthreads();
    for (int i = tid; i < sz; i += 256) {
        unsigned v = ebuf[base + i];
        ein[i] = v;
        atomicAdd(&hist[v >> 17], 1);
    }
    __syncthreads();
    const int deg = hist[tid];
    scn[tid] = deg;
    __syncthreads();
    for (int off = 1; off < 256; off <<= 1) {
        int t = (tid >= off) ? scn[tid - off] : 0;
        __syncthreads();
        scn[tid] += t;
        __syncthreads();
    }
    const int excl = scn[tid] - deg;
    const int node = b * 256 + tid;
    if (node < n) {
        row_off[node] = base + excl;
        dis[node] = rsqrtf((float)deg + 1.0f);
    }
    hist[tid] = excl;           // reuse as cursors
    __syncthreads();
    for (int i = tid; i < sz; i += 256) {
        unsigned v = ein[i];
        int p = atomicAdd(&hist[v >> 17], 1);
        colsrc[base + p] = v & 0x1FFFFu;
    }
}

// Wt packed in MFMA B-fragment order:
// Wt[layer][((c*4+kb)*64 + lane)*8 + j] = bf16(W[layer][kb*32+(lane>>4)*8+j][c*16+(lane&15)])
__global__ void k_prepw(const float* __restrict__ Ws, __hip_bfloat16* __restrict__ Wt) {
    int i = blockIdx.x * blockDim.x + threadIdx.x;   // 4*16384
    int layer = i >> 14;
    int m = i & 16383;
    int j = m & 7;
    int l = (m >> 3) & 63;
    int ckb = m >> 9;
    int kb = ckb & 3;
    int c = ckb >> 2;
    int quad = l >> 4, lr = l & 15;
    int k = kb * 32 + quad * 8 + j;
    int col = c * 16 + lr;
    Wt[i] = __float2bfloat16(Ws[layer * 16384 + k * 128 + col]);
}

// H = X @ W via mfma_f32_16x16x32_bf16. 64 rows/block. Xf != null: layer 0.
__global__ __launch_bounds__(256) void k_matmul(const __hip_bfloat16* __restrict__ Xb,
                                                const float* __restrict__ Xf,
                                                const __hip_bfloat16* __restrict__ Wt,
                                                __hip_bfloat16* __restrict__ Hb, int n) {
    __shared__ __align__(16) __hip_bfloat16 sX[64 * 136];
    const int tid = threadIdx.x;
    const int row0 = blockIdx.x * 64;
    if (Xf) {
        for (int i = tid; i < 2048; i += 256) {
            int r = i >> 5, c = i & 31;
            int gr = row0 + r;
            float4 v = make_float4(0.f, 0.f, 0.f, 0.f);
            if (gr < n) v = *(const float4*)(Xf + (size_t)gr * 128 + c * 4);
            union { bf2 h2[2]; uint2 u; } pk;
            pk.h2[0].x = __float2bfloat16(v.x);
            pk.h2[0].y = __float2bfloat16(v.y);
            pk.h2[1].x = __float2bfloat16(v.z);
            pk.h2[1].y = __float2bfloat16(v.w);
            *(uint2*)(sX + r * 136 + c * 4) = pk.u;
        }
    } else {
        for (int i = tid; i < 1024; i += 256) {
            int r = i >> 4, ck = i & 15;
            uint4 v = make_uint4(0, 0, 0, 0);
            int gr = row0 + r;
            if (gr < n) v = *(const uint4*)(Xb + (size_t)gr * 128 + ck * 8);
            *(uint4*)(sX + r * 136 + ck * 8) = v;
        }
    }
    __syncthreads();
    const int w = tid >> 6, l = tid & 63;
    const int quad = l >> 4, lr = l & 15;
    f32x4 acc[8];
#pragma unroll
    for (int c = 0; c < 8; c++) acc[c] = (f32x4){0.f, 0.f, 0.f, 0.f};
    short8 a[4];
#pragma unroll
    for (int kb = 0; kb < 4; kb++)
        a[kb] = *(const short8*)(sX + (w * 16 + lr) * 136 + kb * 32 + quad * 8);
#pragma unroll
    for (int c = 0; c < 8; c++) {
#pragma unroll
        for (int kb = 0; kb < 4; kb++) {
            short8 b = *(const short8*)(Wt + ((c * 4 + kb) * 64 + l) * 8);
            acc[c] = __builtin_amdgcn_mfma_f32_16x16x32_bf16(a[kb], b, acc[c], 0, 0, 0);
        }
    }
#pragma unroll
    for (int c = 0; c < 8; c++)
#pragma unroll
        for (int r = 0; r < 4; r++)
            sX[(w * 16 + quad * 4 + r) * 136 + c * 16 + lr] =
                __float2bfloat16(acc[c][r]);
#pragma unroll
    for (int p = 0; p < 4; p++) {
        int r = p * 4 + quad;
        int gr = row0 + w * 16 + r;
        uint4 v = *(const uint4*)(sX + (w * 16 + r) * 136 + lr * 8);
        if (gr < n) *(uint4*)(Hb + (size_t)gr * 128 + lr * 8) = v;
    }
}

// 4 nodes per wave; 16-lane group per node, lane sub owns dims [sub*8,sub*8+8).
// colsrc u32 per edge; coef = dis[src]*dis[dst] recomputed (dis L2-hot,
// broadcast across the 16-lane group). 8-edge batched gather, prefetched.
__global__ __launch_bounds__(256) void k_node(const __hip_bfloat16* __restrict__ Hb,
                                              __hip_bfloat16* __restrict__ Xb,
                                              const int* __restrict__ row_off,
                                              const unsigned* __restrict__ colsrc,
                                              const float* __restrict__ dis,
                                              const float* __restrict__ bias,
                                              const float* __restrict__ gamma,
                                              const float* __restrict__ beta,
                                              const float* __restrict__ lin_w,
                                              const int* __restrict__ batch,
                                              float* __restrict__ gsum,
                                              int do_relu, int do_res, int fuse_pool,
                                              int n) {
    __shared__ float spd[16];
    __shared__ int   sbt[16];
    const int wave = threadIdx.x >> 6;
    const int lane = threadIdx.x & 63;
    const int grp = lane >> 4;
    const int sub = lane & 15;
    const int node = blockIdx.x * 16 + wave * 4 + grp;
    const bool vn = node < n;
    const int nd = vn ? node : 0;
    const int e0 = vn ? row_off[node] : 0;
    const int e1 = vn ? row_off[node + 1] : 0;
    const char* hbase = (const char*)Hb;
    const unsigned suboff = (unsigned)(sub << 4);

    float dn = dis[nd];
    uint4 sv = *(const uint4*)(hbase + (((unsigned)nd) << 8) + suboff);

    float acc[8];
#pragma unroll
    for (int k = 0; k < 8; k++) acc[k] = 0.f;

    int e = e0;
    unsigned su[8];
#pragma unroll
    for (int u = 0; u < 8; u++) su[u] = colsrc[(e + u < e1) ? e + u : 0];

    while (__any(e < e1)) {
        uint4 v[8];
        float dv[8];
#pragma unroll
        for (int u = 0; u < 8; u++) {
            v[u] = *(const uint4*)(hbase + (su[u] << 8) + suboff);
            dv[u] = dis[su[u]];
        }
        const int en = e + 8;
        unsigned sn[8];
#pragma unroll
        for (int u = 0; u < 8; u++) sn[u] = colsrc[(en + u < e1) ? en + u : 0];
#pragma unroll
        for (int u = 0; u < 8; u++) {
            float c = (e + u < e1) ? dv[u] * dn : 0.f;
            acc[0] += __uint_as_float(v[u].x << 16) * c;
            acc[1] += __uint_as_float(v[u].x & 0xffff0000u) * c;
            acc[2] += __uint_as_float(v[u].y << 16) * c;
            acc[3] += __uint_as_float(v[u].y & 0xffff0000u) * c;
            acc[4] += __uint_as_float(v[u].z << 16) * c;
            acc[5] += __uint_as_float(v[u].z & 0xffff0000u) * c;
            acc[6] += __uint_as_float(v[u].w << 16) * c;
            acc[7] += __uint_as_float(v[u].w & 0xffff0000u) * c;
        }
#pragma unroll
        for (int u = 0; u < 8; u++) su[u] = sn[u];
        e = en;
    }

    {   // self-loop (preloaded)
        float dn2 = dn * dn;
        acc[0] += __uint_as_float(sv.x << 16) * dn2;
        acc[1] += __uint_as_float(sv.x & 0xffff0000u) * dn2;
        acc[2] += __uint_as_float(sv.y << 16) * dn2;
        acc[3] += __uint_as_float(sv.y & 0xffff0000u) * dn2;
        acc[4] += __uint_as_float(sv.z << 16) * dn2;
        acc[5] += __uint_as_float(sv.z & 0xffff0000u) * dn2;
        acc[6] += __uint_as_float(sv.w << 16) * dn2;
        acc[7] += __uint_as_float(sv.w & 0xffff0000u) * dn2;
    }
    float4 b0 = *(const float4*)(bias + sub * 8);
    float4 b1 = *(const float4*)(bias + sub * 8 + 4);
    acc[0] += b0.x; acc[1] += b0.y; acc[2] += b0.z; acc[3] += b0.w;
    acc[4] += b1.x; acc[5] += b1.y; acc[6] += b1.z; acc[7] += b1.w;

    // LayerNorm within the 16-lane group
    float s = acc[0] + acc[1] + acc[2] + acc[3] + acc[4] + acc[5] + acc[6] + acc[7];
#pragma unroll
    for (int m = 8; m > 0; m >>= 1) s += __shfl_xor(s, m, 64);
    float mu = s * (1.f / 128.f);
    float vs = 0.f;
#pragma unroll
    for (int k = 0; k < 8; k++) {
        float d = acc[k] - mu;
        acc[k] = d;
        vs += d * d;
    }
#pragma unroll
    for (int m = 8; m > 0; m >>= 1) vs += __shfl_xor(vs, m, 64);
    float rs = rsqrtf(vs * (1.f / 128.f) + 1e-5f);

    float4 g0 = *(const float4*)(gamma + sub * 8);
    float4 g1 = *(const float4*)(gamma + sub * 8 + 4);
    float4 t0 = *(const float4*)(beta + sub * 8);
    float4 t1 = *(const float4*)(beta + sub * 8 + 4);
    float y[8];
    y[0] = acc[0] * rs * g0.x + t0.x;
    y[1] = acc[1] * rs * g0.y + t0.y;
    y[2] = acc[2] * rs * g0.z + t0.z;
    y[3] = acc[3] * rs * g0.w + t0.w;
    y[4] = acc[4] * rs * g1.x + t1.x;
    y[5] = acc[5] * rs * g1.y + t1.y;
    y[6] = acc[6] * rs * g1.z + t1.z;
    y[7] = acc[7] * rs * g1.w + t1.w;

    __hip_bfloat16* xp = Xb + (size_t)node * 128 + sub * 8;
    if (vn && do_res) {
        uint4 rv = *(const uint4*)xp;
        y[0] += __uint_as_float(rv.x << 16);
        y[1] += __uint_as_float(rv.x & 0xffff0000u);
        y[2] += __uint_as_float(rv.y << 16);
        y[3] += __uint_as_float(rv.y & 0xffff0000u);
        y[4] += __uint_as_float(rv.z << 16);
        y[5] += __uint_as_float(rv.z & 0xffff0000u);
        y[6] += __uint_as_float(rv.w << 16);
        y[7] += __uint_as_float(rv.w & 0xffff0000u);
    }

    if (fuse_pool) {
        float4 w0 = *(const float4*)(lin_w + sub * 8);
        float4 w1 = *(const float4*)(lin_w + sub * 8 + 4);
        float pdot = y[0] * w0.x + y[1] * w0.y + y[2] * w0.z + y[3] * w0.w +
                     y[4] * w1.x + y[5] * w1.y + y[6] * w1.z + y[7] * w1.w;
#pragma unroll
        for (int m = 8; m > 0; m >>= 1) pdot += __shfl_xor(pdot, m, 64);
        int slot = wave * 4 + grp;
        if (sub == 0) {
            spd[slot] = vn ? pdot : 0.f;
            sbt[slot] = vn ? batch[node] : -1;
        }
        __syncthreads();
        if (threadIdx.x == 0) {
            int i = 0;
            while (i < 16) {
                int b = sbt[i];
                if (b < 0) { i++; continue; }
                float acc2 = spd[i];
                int j = i + 1;
                while (j < 16 && sbt[j] == b) { acc2 += spd[j]; j++; }
                atomicAdd(&gsum[b], acc2);
                i = j;
            }
        }
    } else if (vn) {
        if (do_relu) {
#pragma unroll
            for (int k = 0; k < 8; k++) y[k] = fmaxf(y[k], 0.f);
        }
        union { bf2 h2[4]; uint4 u; } pk;
        pk.h2[0].x = __float2bfloat16(y[0]); pk.h2[0].y = __float2bfloat16(y[1]);
        pk.h2[1].x = __float2bfloat16(y[2]); pk.h2[1].y = __float2bfloat16(y[3]);
        pk.h2[2].x = __float2bfloat16(y[4]); pk.h2[2].y = __float2bfloat16(y[5]);
        pk.h2[3].x = __float2bfloat16(y[6]); pk.h2[3].y = __float2bfloat16(y[7]);
        *(uint4*)xp = pk.u;
    }
}

__global__ void k_out(const float* __restrict__ gsum, const int* __restrict__ batch,
                      const float* __restrict__ lin_b, float* __restrict__ out,
                      int n, int G) {
    int g = blockIdx.x * blockDim.x + threadIdx.x;
    if (g >= G) return;
    int lo = 0, hi = n;
    while (lo < hi) { int m = (lo + hi) >> 1; if (batch[m] < g) lo = m + 1; else hi = m; }
    int start = lo;
    hi = n;
    while (lo < hi) { int m = (lo + hi) >> 1; if (batch[m] <= g) lo = m + 1; else hi = m; }
    float c = (float)(lo - start);
    out[g] = gsum[g] / fmaxf(c, 1.f) + lin_b[0];
}

extern "C" void kernel_launch(void* const* d_in, const int* in_sizes, int n_in,
                              void* d_out, int out_size, void* d_ws, size_t ws_size,
                              hipStream_t stream) {
    const float* x      = (const float*)d_in[0];
    const int*   eidx   = (const int*)d_in[1];
    const int*   batch  = (const int*)d_in[2];
    const float* Ws     = (const float*)d_in[3];
    const float* bs     = (const float*)d_in[4];
    const float* gammas = (const float*)d_in[5];
    const float* betas  = (const float*)d_in[6];
    const float* lin_w  = (const float*)d_in[7];
    const float* lin_b  = (const float*)d_in[8];
    float* out = (float*)d_out;

    const int n = in_sizes[2];        // 100000
    const int E = in_sizes[1] / 2;    // 1600000
    const int G = out_size;           // 512
    const int NB = (n + 255) >> 8;    // 391 buckets

    const int* src  = eidx;
    const int* dstp = eidx + E;

    char* w = (char*)d_ws;
    size_t off = 0;
    auto alloc = [&](size_t bytes) {
        void* p = w + off;
        off = (off + bytes + 15) & ~(size_t)15;
        return p;
    };
    int*      bh      = (int*)     alloc((size_t)P1B * NB * 4);
    int*      btot    = (int*)     alloc((size_t)NB * 4);
    int*      bbase   = (int*)     alloc((size_t)NB * 4);
    unsigned* ebuf    = (unsigned*)alloc((size_t)E * 4);
    unsigned* colsrc  = (unsigned*)alloc((size_t)E * 4);
    int*      row_off = (int*)     alloc((size_t)(n + 1) * 4);
    float*    dis     = (float*)   alloc((size_t)n * 4);
    float*    gsum    = (float*)   alloc((size_t)G * 4);
    __hip_bfloat16* hb = (__hip_bfloat16*)alloc((size_t)n * 128 * 2);
    __hip_bfloat16* xb = (__hip_bfloat16*)alloc((size_t)n * 128 * 2);
    __hip_bfloat16* wt = (__hip_bfloat16*)alloc((size_t)4 * 128 * 128 * 2);
    (void)ws_size; (void)n_in;

    k_p1a<<<P1B, 256, 0, stream>>>(dstp, bh, E, NB);
    k_p1b1<<<NB, 256, 0, stream>>>(bh, btot, NB);
    k_p1b2<<<1, 256, 0, stream>>>(btot, bbase, row_off, gsum, NB, E, n, G);
    k_p1c<<<P1B, 256, 0, stream>>>(src, dstp, bh, bbase, ebuf, E, NB);
    k_p2<<<NB, 256, 0, stream>>>(ebuf, btot, bbase, colsrc, row_off, dis, n);
    k_prepw<<<(4 * 128 * 128 + 255) / 256, 256, 0, stream>>>(Ws, wt);

    for (int layer = 0; layer < 4; layer++) {
        k_matmul<<<(n + 63) / 64, 256, 0, stream>>>(xb, (layer == 0) ? x : nullptr,
                                                    wt + (size_t)layer * 16384, hb, n);
        k_node<<<(n + 15) / 16, 256, 0, stream>>>(hb, xb, row_off, colsrc, dis,
                                                  bs + (size_t)layer * 128,
                                                  gammas + (size_t)layer * 128,
                                                  betas + (size_t)layer * 128,
                                                  lin_w, batch, gsum,
                                                  (layer < 3) ? 1 : 0, (layer > 0) ? 1 : 0,
                                                  (layer == 3) ? 1 : 0, n);
    }
    k_out<<<(G + 255) / 256, 256, 0, stream>>>(gsum, batch, lin_b, out, n, G);
}